// Round 5
// baseline (76.146 us; speedup 1.0000x reference)
//
#include <hip/hip_runtime.h>

#define B_ 8
#define N_ 8192
#define E_ 1024
#define D_ 256
#define ROWS (B_ * N_)          // 65536
#define BE (B_ * E_)            // 8192
#define NT 10                   // tiles: 0..4 = S=(W1+W2), 5..9 = Y2=W2 (col64=membrane)
#define KT 8                    // K = 256 (obs only)

typedef float  f32x4  __attribute__((ext_vector_type(4)));
typedef __bf16 bf16x8 __attribute__((ext_vector_type(8)));

// ---- workspace layout (f32 units) ----
#define SE_OFF  0                        // ROWS*64 : s_e
#define SM_OFF  (ROWS * 64)              // ROWS    : s_membrane
#define YS_OFF  (SM_OFF + ROWS)          // BE*80   : bucket y2 sums (col 64 = membrane)
#define CNT_OFF (YS_OFF + BE * 80)       // BE      : bucket counts (as f32)
#define WEF_OFF (CNT_OFF + BE)           // bf16 region starts here (80 KB)

__global__ __launch_bounds__(1024) void zero_kernel(float* __restrict__ ws) {
    // zero ysum + cnt: BE*80 + BE = 663552 f32 = 165888 f32x4 (exactly 162*1024)
    f32x4* p = (f32x4*)(ws + YS_OFF);
    p[blockIdx.x * 1024 + threadIdx.x] = (f32x4){0.f, 0.f, 0.f, 0.f};
}

// pack W' fragments: wef[((kt*NT+nt)*64+lane)*8+i] = W'[nt*16+(lane&15)][kt*32+(lane>>4)*8+i]
// W' rows r (0..63 = e-cols, 64 = membrane, 65..79 = zero pad)
// S group (nt<5):  W1[r][k] + W2[r][k]  ; Y2 group (nt>=5): W2[r][k]
__global__ __launch_bounds__(256) void wef_kernel(const float* __restrict__ we,
                                                  const float* __restrict__ wm,
                                                  __bf16* __restrict__ wef) {
    const int t = blockIdx.x * 256 + threadIdx.x;   // 0..5119
    const int lane = t & 63;
    const int nt = (t >> 6) % NT;
    const int kt = t / (NT * 64);
    const int grp = nt / 5;          // 0 = S, 1 = Y2
    const int r   = (nt % 5) * 16 + (lane & 15);
    const int k0  = kt * 32 + (lane >> 4) * 8;
    bf16x8 v;
#pragma unroll
    for (int i = 0; i < 8; ++i) {
        const int k = k0 + i;
        float f = 0.f;
        if (r < 64)       f = grp ? we[r * 512 + 256 + k] : we[r * 512 + k] + we[r * 512 + 256 + k];
        else if (r == 64) f = grp ? wm[256 + k]           : wm[k] + wm[256 + k];
        v[i] = (__bf16)f;
    }
    *(bf16x8*)(wef + (size_t)t * 8) = v;
}

// GEMM: [65536 x 256] @ [256 x 160(padded)] -> s (written) + y2 (atomically bucket-summed)
__global__ __launch_bounds__(256) void gemm_kernel(
    const float* __restrict__ obs, const int* __restrict__ idx,
    const __bf16* __restrict__ wef, float* __restrict__ ws) {

    const int tid = threadIdx.x;
    const int l   = tid & 63;
    const int rw0 = blockIdx.x * 128 + (tid >> 6) * 32;
    const int r0  = rw0 + (l & 15);
    const int r1  = r0 + 16;
    const int q8  = (l >> 4) << 3;

    f32x4 acc[2][NT];
#pragma unroll
    for (int a = 0; a < 2; ++a)
#pragma unroll
        for (int b = 0; b < NT; ++b) acc[a][b] = (f32x4){0.f, 0.f, 0.f, 0.f};

    const float* o0 = obs + (((size_t)r0) << 8) + q8;
    const float* o1 = obs + (((size_t)r1) << 8) + q8;

#pragma unroll
    for (int g = 0; g < KT; ++g) {
        const f32x4 oa0 = *(const f32x4*)(o0 + g * 32);
        const f32x4 ob0 = *(const f32x4*)(o0 + g * 32 + 4);
        const f32x4 oa1 = *(const f32x4*)(o1 + g * 32);
        const f32x4 ob1 = *(const f32x4*)(o1 + g * 32 + 4);
        bf16x8 A0, A1;
#pragma unroll
        for (int i = 0; i < 4; ++i) {
            A0[i] = (__bf16)oa0[i];  A0[4 + i] = (__bf16)ob0[i];
            A1[i] = (__bf16)oa1[i];  A1[4 + i] = (__bf16)ob1[i];
        }
#pragma unroll
        for (int nt = 0; nt < NT; ++nt) {
            const bf16x8 bb = *(const bf16x8*)(wef + (size_t)(((g * NT + nt) << 6) + l) * 8);
            acc[0][nt] = __builtin_amdgcn_mfma_f32_16x16x32_bf16(A0, bb, acc[0][nt], 0, 0, 0);
            acc[1][nt] = __builtin_amdgcn_mfma_f32_16x16x32_bf16(A1, bb, acc[1][nt], 0, 0, 0);
        }
    }

    float* sE  = ws + SE_OFF;
    float* sM  = ws + SM_OFF;
    float* ys  = ws + YS_OFF;
    float* cnt = ws + CNT_OFF;

    const int cgrp = (l >> 4) << 2;
    const int c16  = l & 15;
#pragma unroll
    for (int rt = 0; rt < 2; ++rt) {
#pragma unroll
        for (int j = 0; j < 4; ++j) {
            const int row = rw0 + rt * 16 + cgrp + j;
            const int bei = ((row >> 13) << 10) + idx[row];
            // s part
#pragma unroll
            for (int nt = 0; nt < 4; ++nt)
                sE[((size_t)row << 6) + (nt << 4) + c16] = acc[rt][nt][j];
            if (c16 == 0) sM[row] = acc[rt][4][j];
            // y2 bucket sums
#pragma unroll
            for (int nt = 0; nt < 4; ++nt)
                atomicAdd(&ys[(size_t)bei * 80 + (nt << 4) + c16], acc[rt][5 + nt][j]);
            if (c16 == 0) {
                atomicAdd(&ys[(size_t)bei * 80 + 64], acc[rt][9][j]);
                atomicAdd(&cnt[bei], 1.0f);
            }
        }
    }
}

// final: e = (s_e - ysum_e/cnt + b_e) * g * mask ;  g = sigmoid(s_m - ysum_m/cnt + b_m) * mask
__global__ __launch_bounds__(256) void final_kernel(
    const float* __restrict__ mask, const int* __restrict__ idx,
    const float* __restrict__ bmp, const float* __restrict__ bep,
    const float* __restrict__ ws, float* __restrict__ out) {

    const int t   = threadIdx.x;
    const int row = blockIdx.x * 4 + (t >> 6);
    const int l   = t & 63;

    const float* sE  = ws + SE_OFF;
    const float* sM  = ws + SM_OFF;
    const float* ys  = ws + YS_OFF;
    const float* cnt = ws + CNT_OFF;

    const int bei   = ((row >> 13) << 10) + idx[row];
    const float inv = 1.f / fmaxf(cnt[bei], 1.f);
    const float mk  = mask[row];
    const float m   = sM[row] - ys[(size_t)bei * 80 + 64] * inv + bmp[0];
    const float g   = mk / (1.f + __expf(-m));
    const float e   = (sE[((size_t)row << 6) + l] - ys[(size_t)bei * 80 + l] * inv + bep[l]) * g * mk;

    out[(size_t)ROWS + ((size_t)row << 6) + l] = e;
    if (l == 0) out[row] = g;
}

extern "C" void kernel_launch(void* const* d_in, const int* in_sizes, int n_in,
                              void* d_out, int out_size, void* d_ws, size_t ws_size,
                              hipStream_t stream) {
    (void)in_sizes; (void)n_in; (void)out_size; (void)ws_size;
    const float* obs  = (const float*)d_in[0];
    const float* mask = (const float*)d_in[1];
    // d_in[2] = incidence: one-hot of idx, never read (saves 268 MB of traffic)
    const int*   idx  = (const int*)d_in[3];
    const float* w_m  = (const float*)d_in[4];
    const float* b_m  = (const float*)d_in[5];
    const float* w_e  = (const float*)d_in[6];
    const float* b_e  = (const float*)d_in[7];

    float*  ws  = (float*)d_ws;
    __bf16* wef = (__bf16*)(ws + WEF_OFF);

    zero_kernel<<<162, 1024, 0, stream>>>(ws);                       // ysum + cnt
    wef_kernel<<<KT * NT * 64 / 256, 256, 0, stream>>>(w_e, w_m, wef);
    gemm_kernel<<<ROWS / 128, 256, 0, stream>>>(obs, idx, wef, ws);
    final_kernel<<<ROWS / 4, 256, 0, stream>>>(mask, idx, b_m, b_e, ws, (float*)d_out);
}

// Round 6
// 64.204 us; speedup vs baseline: 1.1860x; 1.1860x over previous
//
#include <hip/hip_runtime.h>

#define B_ 8
#define N_ 8192
#define E_ 1024
#define ROWS (B_ * N_)          // 65536
#define BE (B_ * E_)            // 8192
#define NT 10                   // 0..4 = S=(W1+W2) proj, 5..9 = Y2=W2 proj (col64 = membrane)
#define KT 8                    // K = 256

typedef float  f32x4  __attribute__((ext_vector_type(4)));
typedef __bf16 bf16x8 __attribute__((ext_vector_type(8)));

// ---- workspace layout (byte offsets) ----
#define SE16_OFF  0                           // ROWS*64 bf16  (8.39 MB)
#define SM16_OFF  (SE16_OFF + ROWS * 64 * 2)  // ROWS bf16
#define Y2E_OFF   (SM16_OFF + ROWS * 2)       // ROWS*64 bf16  (8.39 MB)
#define Y2M_OFF   (Y2E_OFF + ROWS * 64 * 2)   // ROWS bf16
#define YS_OFF    (Y2M_OFF + ROWS * 2)        // BE*80 f32 (cols 0..63 e, 64 membrane, 65 cnt)
#define HIST_OFF  (YS_OFF + BE * 80 * 4)      // BE u32
#define CURS_OFF  (HIST_OFF + BE * 4)         // BE u32
#define ORD_OFF   (CURS_OFF + BE * 4)         // ROWS u32
#define WEF_OFF   (ORD_OFF + ROWS * 4)        // KT*NT*64*8 bf16 (80 KB) -> total ~20.1 MB

__device__ inline float bflo(unsigned u) { return __uint_as_float(u << 16); }
__device__ inline float bfhi(unsigned u) { return __uint_as_float(u & 0xffff0000u); }

__global__ __launch_bounds__(1024) void zero_kernel(unsigned* __restrict__ p) {
    p[blockIdx.x * 1024 + threadIdx.x] = 0u;          // hist + cursor (16384 u32)
}

// blocks 0..255: histogram of idx. blocks 256..275: pack W' fragments.
// wef[((kt*NT+nt)*64+lane)*8+i] = W'[(nt%5)*16+(lane&15)][kt*32+(lane>>4)*8+i]
// grp = nt/5: 0 -> W1+W2 (S), 1 -> W2 (Y2); row 64 = membrane (w_m), 65..79 zero.
__global__ __launch_bounds__(256) void histwef_kernel(
    const int* __restrict__ idx, unsigned* __restrict__ hist,
    const float* __restrict__ we, const float* __restrict__ wm,
    __bf16* __restrict__ wef) {
    const int bid = blockIdx.x;
    if (bid < 256) {
        const int row = bid * 256 + threadIdx.x;
        atomicAdd(&hist[((row >> 13) << 10) + idx[row]], 1u);
    } else {
        const int t = (bid - 256) * 256 + threadIdx.x;   // 0..5119
        const int lane = t & 63;
        const int nt = (t >> 6) % NT;
        const int kt = t / (NT * 64);
        const int grp = nt / 5;
        const int r   = (nt % 5) * 16 + (lane & 15);
        const int k0  = kt * 32 + (lane >> 4) * 8;
        bf16x8 v;
#pragma unroll
        for (int i = 0; i < 8; ++i) {
            const int k = k0 + i;
            float f = 0.f;
            if (r < 64)       f = grp ? we[r * 512 + 256 + k] : we[r * 512 + k] + we[r * 512 + 256 + k];
            else if (r == 64) f = grp ? wm[256 + k]           : wm[k] + wm[256 + k];
            v[i] = (__bf16)f;
        }
        *(bf16x8*)(wef + (size_t)t * 8) = v;
    }
}

// exclusive scan of hist (8192) -> cursor. One block, shfl-based.
__global__ __launch_bounds__(256) void scan_kernel(const unsigned* __restrict__ hist,
                                                   unsigned* __restrict__ cursor) {
    __shared__ unsigned wsums[4];
    const int t = threadIdx.x;
    unsigned loc[32], s = 0;
#pragma unroll
    for (int i = 0; i < 32; ++i) { loc[i] = hist[t * 32 + i]; s += loc[i]; }
    unsigned inc = s;
#pragma unroll
    for (int off = 1; off < 64; off <<= 1) {
        const unsigned v = __shfl_up(inc, off);
        if ((t & 63) >= off) inc += v;
    }
    if ((t & 63) == 63) wsums[t >> 6] = inc;
    __syncthreads();
    unsigned run = inc - s;
    for (int w = 0; w < (t >> 6); ++w) run += wsums[w];
#pragma unroll
    for (int i = 0; i < 32; ++i) { cursor[t * 32 + i] = run; run += loc[i]; }
}

__global__ __launch_bounds__(256) void fill_kernel(const int* __restrict__ idx,
                                                   unsigned* __restrict__ cursor,
                                                   unsigned* __restrict__ order) {
    const int row = blockIdx.x * 256 + threadIdx.x;
    const int bei = ((row >> 13) << 10) + idx[row];
    order[atomicAdd(&cursor[bei], 1u)] = (unsigned)row;
}

// GEMM: [65536 x 256] @ [256 x 160(padded)] -> sE/sM + y2e/y2m, all bf16, plain stores.
__global__ __launch_bounds__(256) void gemm_kernel(
    const float* __restrict__ obs, const __bf16* __restrict__ wef,
    char* __restrict__ ws) {

    const int tid = threadIdx.x;
    const int l   = tid & 63;
    const int rw0 = blockIdx.x * 128 + (tid >> 6) * 32;
    const int r0  = rw0 + (l & 15);
    const int r1  = r0 + 16;
    const int q8  = (l >> 4) << 3;

    f32x4 acc[2][NT];
#pragma unroll
    for (int a = 0; a < 2; ++a)
#pragma unroll
        for (int b = 0; b < NT; ++b) acc[a][b] = (f32x4){0.f, 0.f, 0.f, 0.f};

    const float* o0 = obs + (((size_t)r0) << 8) + q8;
    const float* o1 = obs + (((size_t)r1) << 8) + q8;

#pragma unroll
    for (int g = 0; g < KT; ++g) {
        const f32x4 oa0 = *(const f32x4*)(o0 + g * 32);
        const f32x4 ob0 = *(const f32x4*)(o0 + g * 32 + 4);
        const f32x4 oa1 = *(const f32x4*)(o1 + g * 32);
        const f32x4 ob1 = *(const f32x4*)(o1 + g * 32 + 4);
        bf16x8 A0, A1;
#pragma unroll
        for (int i = 0; i < 4; ++i) {
            A0[i] = (__bf16)oa0[i];  A0[4 + i] = (__bf16)ob0[i];
            A1[i] = (__bf16)oa1[i];  A1[4 + i] = (__bf16)ob1[i];
        }
#pragma unroll
        for (int nt = 0; nt < NT; ++nt) {
            const bf16x8 bb = *(const bf16x8*)(wef + (size_t)(((g * NT + nt) << 6) + l) * 8);
            acc[0][nt] = __builtin_amdgcn_mfma_f32_16x16x32_bf16(A0, bb, acc[0][nt], 0, 0, 0);
            acc[1][nt] = __builtin_amdgcn_mfma_f32_16x16x32_bf16(A1, bb, acc[1][nt], 0, 0, 0);
        }
    }

    __bf16* sE  = (__bf16*)(ws + SE16_OFF);
    __bf16* sM  = (__bf16*)(ws + SM16_OFF);
    __bf16* y2e = (__bf16*)(ws + Y2E_OFF);
    __bf16* y2m = (__bf16*)(ws + Y2M_OFF);

    const int cgrp = (l >> 4) << 2;
    const int c16  = l & 15;
#pragma unroll
    for (int rt = 0; rt < 2; ++rt) {
#pragma unroll
        for (int j = 0; j < 4; ++j) {
            const int row = rw0 + rt * 16 + cgrp + j;
#pragma unroll
            for (int nt = 0; nt < 4; ++nt) {
                sE [((size_t)row << 6) + (nt << 4) + c16] = (__bf16)acc[rt][nt][j];
                y2e[((size_t)row << 6) + (nt << 4) + c16] = (__bf16)acc[rt][5 + nt][j];
            }
            if (c16 == 0) {
                sM [row] = (__bf16)acc[rt][4][j];
                y2m[row] = (__bf16)acc[rt][9][j];
            }
        }
    }
}

// per-bucket segment sum of y2 (bf16 -> f32), plain stores. One wave per bucket.
__global__ __launch_bounds__(256) void ysum_kernel(
    const unsigned* __restrict__ hist, const unsigned* __restrict__ cursor,
    const unsigned* __restrict__ order, char* __restrict__ ws) {

    const int bucket = blockIdx.x * 4 + (threadIdx.x >> 6);
    const int l  = threadIdx.x & 63;
    const int lc = l & 31;          // col pair (2lc, 2lc+1)
    const int hi = l >> 5;          // half-wave: even/odd members

    const unsigned short* y2e = (const unsigned short*)(ws + Y2E_OFF);
    const unsigned short* y2m = (const unsigned short*)(ws + Y2M_OFF);
    float* ys = (float*)(ws + YS_OFF);

    const unsigned len   = hist[bucket];
    const unsigned start = cursor[bucket] - len;   // cursor = end after fill

    float ax = 0.f, ay = 0.f;
    for (unsigned i = hi; i < len; i += 2) {
        const unsigned orow = order[start + i];
        const unsigned u = *(const unsigned*)(y2e + ((size_t)orow << 6) + lc * 2);
        ax += bflo(u); ay += bfhi(u);
    }
    float mm = 0.f;
    for (unsigned i = l; i < len; i += 64) {
        const unsigned orow = order[start + i];
        mm += bflo(y2m[orow]);
    }
    ax += __shfl_xor(ax, 32);
    ay += __shfl_xor(ay, 32);
#pragma unroll
    for (int off = 1; off < 64; off <<= 1) mm += __shfl_xor(mm, off);

    if (l < 32) {
        ys[(size_t)bucket * 80 + 2 * l]     = ax;
        ys[(size_t)bucket * 80 + 2 * l + 1] = ay;
    }
    if (l == 0) {
        ys[(size_t)bucket * 80 + 64] = mm;
        ys[(size_t)bucket * 80 + 65] = (float)len;
    }
}

// final: g = sigmoid(sM - ysM/cnt + bm)*mask ; e = (sE - ysE/cnt + be)*g*mask
__global__ __launch_bounds__(256) void final_kernel(
    const float* __restrict__ mask, const int* __restrict__ idx,
    const float* __restrict__ bmp, const float* __restrict__ bep,
    const char* __restrict__ ws, float* __restrict__ out) {

    const int t   = threadIdx.x;
    const int row = blockIdx.x * 4 + (t >> 6);
    const int l   = t & 63;

    const unsigned short* sE = (const unsigned short*)(ws + SE16_OFF);
    const unsigned short* sM = (const unsigned short*)(ws + SM16_OFF);
    const float* ys = (const float*)(ws + YS_OFF);

    const int bei   = ((row >> 13) << 10) + idx[row];
    const float cnt = ys[(size_t)bei * 80 + 65];
    const float inv = 1.f / fmaxf(cnt, 1.f);
    const float mk  = mask[row];
    const float m   = bflo(sM[row]) - ys[(size_t)bei * 80 + 64] * inv + bmp[0];
    const float g   = mk / (1.f + __expf(-m));
    const float e   = (bflo(sE[((size_t)row << 6) + l]) - ys[(size_t)bei * 80 + l] * inv + bep[l]) * g * mk;

    out[(size_t)ROWS + ((size_t)row << 6) + l] = e;
    if (l == 0) out[row] = g;
}

extern "C" void kernel_launch(void* const* d_in, const int* in_sizes, int n_in,
                              void* d_out, int out_size, void* d_ws, size_t ws_size,
                              hipStream_t stream) {
    (void)in_sizes; (void)n_in; (void)out_size; (void)ws_size;
    const float* obs  = (const float*)d_in[0];
    const float* mask = (const float*)d_in[1];
    // d_in[2] = incidence: one-hot of idx, never read (saves 268 MB of traffic)
    const int*   idx  = (const int*)d_in[3];
    const float* w_m  = (const float*)d_in[4];
    const float* b_m  = (const float*)d_in[5];
    const float* w_e  = (const float*)d_in[6];
    const float* b_e  = (const float*)d_in[7];

    char* ws = (char*)d_ws;
    unsigned* hist   = (unsigned*)(ws + HIST_OFF);
    unsigned* cursor = (unsigned*)(ws + CURS_OFF);
    unsigned* order  = (unsigned*)(ws + ORD_OFF);
    __bf16*   wef    = (__bf16*)(ws + WEF_OFF);

    zero_kernel<<<16, 1024, 0, stream>>>(hist);                       // hist + cursor
    histwef_kernel<<<276, 256, 0, stream>>>(idx, hist, w_e, w_m, wef);
    gemm_kernel<<<ROWS / 128, 256, 0, stream>>>(obs, wef, ws);
    scan_kernel<<<1, 256, 0, stream>>>(hist, cursor);
    fill_kernel<<<ROWS / 256, 256, 0, stream>>>(idx, cursor, order);
    ysum_kernel<<<BE / 4, 256, 0, stream>>>(hist, cursor, order, ws);
    final_kernel<<<ROWS / 4, 256, 0, stream>>>(mask, idx, b_m, b_e, ws, (float*)d_out);
}

// Round 7
// 46.359 us; speedup vs baseline: 1.6425x; 1.3849x over previous
//
#include <hip/hip_runtime.h>

#define B_ 8
#define N_ 8192
#define E_ 1024
#define ROWS (B_ * N_)          // 65536
#define BE (B_ * E_)            // 8192
#define NT 10                   // 0..4 = S=(W1+W2) proj, 5..9 = Y2=W2 proj (col 64 = membrane)
#define KT 8                    // K = 256

typedef float  f32x4  __attribute__((ext_vector_type(4)));
typedef __bf16 bf16x8 __attribute__((ext_vector_type(8)));

// ---- workspace layout (byte offsets). All bulk arrays indexed by SORTED dest. ----
#define SE16_OFF  0                            // ROWS*64 bf16 (8.39 MB)
#define SM16_OFF  (SE16_OFF + ROWS * 64 * 2)   // ROWS bf16
#define Y2E_OFF   (SM16_OFF + ROWS * 2)        // ROWS*64 bf16 (8.39 MB)
#define Y2M_OFF   (Y2E_OFF + ROWS * 64 * 2)    // ROWS bf16
#define SEG_OFF   (Y2M_OFF + ROWS * 2)         // BE uint2 {start,len}
#define SP_OFF    (SEG_OFF + BE * 8)           // ROWS u32 : row -> sorted dest
#define ORD_OFF   (SP_OFF + ROWS * 4)          // ROWS u32 : sorted dest -> row
#define WEF_OFF   (ORD_OFF + ROWS * 4)         // KT*NT*64*8 bf16 (80 KB) -> ~17.7 MB total

__device__ inline float bflo(unsigned u) { return __uint_as_float(u << 16); }
__device__ inline float bfhi(unsigned u) { return __uint_as_float(u & 0xffff0000u); }

// blocks 0..7: per-batch LDS bucketize (hist+scan+fill, zero global atomics).
// blocks 8..12: pack W' fragments.
// wef[((kt*NT+nt)*64+lane)*8+i] = W'[(nt%5)*16+(lane&15)][kt*32+(lane>>4)*8+i]
//   grp = nt/5: 0 -> W1+W2 (S), 1 -> W2 (Y2); row 64 = w_m, 65..79 zero.
__global__ __launch_bounds__(1024) void bucketize_kernel(
    const int* __restrict__ idx, const float* __restrict__ we,
    const float* __restrict__ wm, char* __restrict__ ws) {

    const int bid = blockIdx.x;
    if (bid >= 8) {                            // ---- wef packing ----
        const int t = (bid - 8) * 1024 + threadIdx.x;   // 0..5119
        if (t >= KT * NT * 64) return;
        __bf16* wef = (__bf16*)(ws + WEF_OFF);
        const int lane = t & 63;
        const int nt = (t >> 6) % NT;
        const int kt = t / (NT * 64);
        const int grp = nt / 5;
        const int r   = (nt % 5) * 16 + (lane & 15);
        const int k0  = kt * 32 + (lane >> 4) * 8;
        bf16x8 v;
#pragma unroll
        for (int i = 0; i < 8; ++i) {
            const int k = k0 + i;
            float f = 0.f;
            if (r < 64)       f = grp ? we[r * 512 + 256 + k] : we[r * 512 + k] + we[r * 512 + 256 + k];
            else if (r == 64) f = grp ? wm[256 + k]           : wm[k] + wm[256 + k];
            v[i] = (__bf16)f;
        }
        *(bf16x8*)(wef + (size_t)t * 8) = v;
        return;
    }

    // ---- per-batch bucketize: batch b, 1024 threads, LDS hist/scan/cursor ----
    __shared__ unsigned h[1024];
    __shared__ unsigned wpart[16];
    const int b = bid;
    const int t = threadIdx.x;
    const int lane = t & 63;
    const int w = t >> 6;

    h[t] = 0u;
    __syncthreads();

    unsigned my[8];
#pragma unroll
    for (int i = 0; i < 8; ++i) my[i] = (unsigned)idx[(b << 13) + (i << 10) + t];
#pragma unroll
    for (int i = 0; i < 8; ++i) atomicAdd(&h[my[i]], 1u);
    __syncthreads();

    const unsigned v = h[t];
    unsigned inc = v;
#pragma unroll
    for (int off = 1; off < 64; off <<= 1) {
        const unsigned u = __shfl_up(inc, off);
        if (lane >= off) inc += u;
    }
    if (lane == 63) wpart[w] = inc;
    __syncthreads();
    unsigned add = 0;
    for (int ww = 0; ww < w; ++ww) add += wpart[ww];
    const unsigned base = add + inc - v;               // exclusive scan within batch

    ((uint2*)(ws + SEG_OFF))[(b << 10) + t] = (uint2){(unsigned)(b << 13) + base, v};
    __syncthreads();
    h[t] = base;                                       // reuse hist as cursor
    __syncthreads();

    unsigned* sortpos = (unsigned*)(ws + SP_OFF);
    unsigned* order   = (unsigned*)(ws + ORD_OFF);
#pragma unroll
    for (int i = 0; i < 8; ++i) {
        const unsigned p   = atomicAdd(&h[my[i]], 1u);
        const unsigned row = (unsigned)(b << 13) + (i << 10) + t;
        const unsigned d   = (unsigned)(b << 13) + p;
        sortpos[row] = d;
        order[d]     = row;
    }
}

// GEMM: [65536 x 256] @ [256 x 160(pad)] -> sE/sM + y2e/y2m (bf16), scatter-written
// at the sorted dest so the tail kernel reads pure contiguous segments.
__global__ __launch_bounds__(256) void gemm_kernel(
    const float* __restrict__ obs, const __bf16* __restrict__ wef,
    char* __restrict__ ws) {

    const int tid = threadIdx.x;
    const int l   = tid & 63;
    const int rw0 = blockIdx.x * 128 + (tid >> 6) * 32;
    const int r0  = rw0 + (l & 15);
    const int r1  = r0 + 16;
    const int q8  = (l >> 4) << 3;

    f32x4 acc[2][NT];
#pragma unroll
    for (int a = 0; a < 2; ++a)
#pragma unroll
        for (int b = 0; b < NT; ++b) acc[a][b] = (f32x4){0.f, 0.f, 0.f, 0.f};

    const float* o0 = obs + (((size_t)r0) << 8) + q8;
    const float* o1 = obs + (((size_t)r1) << 8) + q8;

#pragma unroll
    for (int g = 0; g < KT; ++g) {
        const f32x4 oa0 = *(const f32x4*)(o0 + g * 32);
        const f32x4 ob0 = *(const f32x4*)(o0 + g * 32 + 4);
        const f32x4 oa1 = *(const f32x4*)(o1 + g * 32);
        const f32x4 ob1 = *(const f32x4*)(o1 + g * 32 + 4);
        bf16x8 A0, A1;
#pragma unroll
        for (int i = 0; i < 4; ++i) {
            A0[i] = (__bf16)oa0[i];  A0[4 + i] = (__bf16)ob0[i];
            A1[i] = (__bf16)oa1[i];  A1[4 + i] = (__bf16)ob1[i];
        }
#pragma unroll
        for (int nt = 0; nt < NT; ++nt) {
            const bf16x8 bb = *(const bf16x8*)(wef + (size_t)(((g * NT + nt) << 6) + l) * 8);
            acc[0][nt] = __builtin_amdgcn_mfma_f32_16x16x32_bf16(A0, bb, acc[0][nt], 0, 0, 0);
            acc[1][nt] = __builtin_amdgcn_mfma_f32_16x16x32_bf16(A1, bb, acc[1][nt], 0, 0, 0);
        }
    }

    __bf16* sE  = (__bf16*)(ws + SE16_OFF);
    __bf16* sM  = (__bf16*)(ws + SM16_OFF);
    __bf16* y2e = (__bf16*)(ws + Y2E_OFF);
    __bf16* y2m = (__bf16*)(ws + Y2M_OFF);
    const unsigned* sortpos = (const unsigned*)(ws + SP_OFF);

    const int cgrp = (l >> 4) << 2;
    const int c16  = l & 15;
#pragma unroll
    for (int rt = 0; rt < 2; ++rt) {
#pragma unroll
        for (int j = 0; j < 4; ++j) {
            const int row = rw0 + rt * 16 + cgrp + j;
            const unsigned dp = sortpos[row];          // 16-lane broadcast load
#pragma unroll
            for (int nt = 0; nt < 4; ++nt) {
                sE [((size_t)dp << 6) + (nt << 4) + c16] = (__bf16)acc[rt][nt][j];
                y2e[((size_t)dp << 6) + (nt << 4) + c16] = (__bf16)acc[rt][5 + nt][j];
            }
            if (c16 == 0) {
                sM [dp] = (__bf16)acc[rt][4][j];
                y2m[dp] = (__bf16)acc[rt][9][j];
            }
        }
    }
}

// tail: one wave per bucket. Phase 1: contiguous segment-sum of y2 -> in-register means.
// Phase 2: apply final math to the bucket's member rows and write g_n / e_n.
__global__ __launch_bounds__(256) void tail_kernel(
    const float* __restrict__ mask, const float* __restrict__ bmp,
    const float* __restrict__ bep, const char* __restrict__ ws,
    float* __restrict__ out) {

    const int bucket = blockIdx.x * 4 + (threadIdx.x >> 6);
    const int l  = threadIdx.x & 63;
    const int lc = l & 31;          // col pair (2lc, 2lc+1)
    const int hi = l >> 5;          // member parity

    const uint2 sg = ((const uint2*)(ws + SEG_OFF))[bucket];
    const unsigned start = sg.x, len = sg.y;
    if (len == 0) return;                              // wave-private bucket, safe

    const unsigned*       y2eu = (const unsigned*)(ws + Y2E_OFF);
    const unsigned short* y2m  = (const unsigned short*)(ws + Y2M_OFF);

    float ax = 0.f, ay = 0.f;
    for (unsigned i = hi; i < len; i += 2) {
        const unsigned u = y2eu[(size_t)(start + i) * 32 + lc];
        ax += bflo(u); ay += bfhi(u);
    }
    ax += __shfl_xor(ax, 32);
    ay += __shfl_xor(ay, 32);

    float mm = 0.f;
    for (unsigned i = l; i < len; i += 64) mm += bflo(y2m[start + i]);
#pragma unroll
    for (int off = 1; off < 64; off <<= 1) mm += __shfl_xor(mm, off);

    const float inv = 1.f / (float)len;
    const float meL = ax * inv, meH = ay * inv, mM = mm * inv;
    const float bm  = bmp[0];
    const float beL = bep[2 * lc], beH = bep[2 * lc + 1];

    const unsigned*       sEu  = (const unsigned*)(ws + SE16_OFF);
    const unsigned short* sM16 = (const unsigned short*)(ws + SM16_OFF);
    const unsigned*       ordu = (const unsigned*)(ws + ORD_OFF);

    for (unsigned i = hi; i < len; i += 2) {
        const unsigned d   = start + i;
        const unsigned row = ordu[d];
        const unsigned u   = sEu[(size_t)d * 32 + lc];
        const float sm = bflo(sM16[d]);
        const float mk = mask[row];
        const float m  = sm - mM + bm;
        const float g  = mk / (1.f + __expf(-m));
        float2 e;
        e.x = (bflo(u) - meL + beL) * g * mk;
        e.y = (bfhi(u) - meH + beH) * g * mk;
        *(float2*)(out + (size_t)ROWS + ((size_t)row << 6) + 2 * lc) = e;
        if (lc == 0) out[row] = g;
    }
}

extern "C" void kernel_launch(void* const* d_in, const int* in_sizes, int n_in,
                              void* d_out, int out_size, void* d_ws, size_t ws_size,
                              hipStream_t stream) {
    (void)in_sizes; (void)n_in; (void)out_size; (void)ws_size;
    const float* obs  = (const float*)d_in[0];
    const float* mask = (const float*)d_in[1];
    // d_in[2] = incidence: one-hot of idx, never read (saves 268 MB of traffic)
    const int*   idx  = (const int*)d_in[3];
    const float* w_m  = (const float*)d_in[4];
    const float* b_m  = (const float*)d_in[5];
    const float* w_e  = (const float*)d_in[6];
    const float* b_e  = (const float*)d_in[7];

    char*   ws  = (char*)d_ws;
    __bf16* wef = (__bf16*)(ws + WEF_OFF);

    bucketize_kernel<<<13, 1024, 0, stream>>>(idx, w_e, w_m, ws);
    gemm_kernel<<<ROWS / 128, 256, 0, stream>>>(obs, wef, ws);
    tail_kernel<<<BE / 4, 256, 0, stream>>>(mask, b_m, b_e, ws, (float*)d_out);
}